// Round 2
// baseline (543.255 us; speedup 1.0000x reference)
//
#include <hip/hip_runtime.h>
#include <cmath>

#define SOS 0
#define EOS 1
#define Bb 128
#define Ss 1024
#define Tt 128
#define LOG2E 1.4426950408889634f
#define LN2f  0.6931471805599453f

// ---------------------------------------------------------------------------
// Forward (partition) kernel: one block (4 waves) per batch element.
// Linear-space recurrence, j-split across waves:
//   wave w owns cols j in [32w,32w+32); lane: col = l&31, khalf = l>>5.
//   Each lane: 64 FMAs over its k-half with register-resident exp(trans),
//   then one __shfl_xor(32) completes the 128-deep dot product.
// ONE barrier + ONE LDS f round-trip per step (s_f double-buffered).
// Emissions prefetched 2 steps ahead into registers (coalesced loads).
// Rescale: measure max (5 shuffles) at i%4==0, apply at i%4==1 by folding
// 2^-e into the emission weight (single mul on the output).
// ---------------------------------------------------------------------------
__global__ __launch_bounds__(256) void crf_forward(
    const float* __restrict__ em, const float* __restrict__ trans,
    const float* __restrict__ mask, float* __restrict__ part_out)
{
  __shared__ __align__(16) float s_trans[Tt * Tt];   // 64 KB (prologue only)
  __shared__ __align__(16) float s_f[2][Tt];
  __shared__ __align__(16) float s_red[4];
  __shared__ __align__(16) float s_mask[Ss];

  const int tid = threadIdx.x;
  const int w   = tid >> 6;
  const int l   = tid & 63;
  const int jl  = l & 31;
  const int j   = w * 32 + jl;     // this lane's output column
  const int kh  = l >> 5;          // k-half: 0 or 1
  const int kbase = kh * 64;
  const int b   = blockIdx.x;
  const size_t base = (size_t)b * Ss * Tt;

  // ---- prologue: stage mask + transition ----
  for (int i = tid; i < Ss; i += 256) s_mask[i] = mask[b * Ss + i];
  #pragma unroll
  for (int it = 0; it < 16; ++it) {
    int idx = (it * 256 + tid) * 4;
    *(float4*)&s_trans[idx] = *(const float4*)&trans[idx];
  }
  if (tid < 4) s_red[tid] = 0.5f;   // frexp(0.5) -> e=0 -> first apply is no-op
  __syncthreads();

  // register-resident column slice of exp(trans): M[k][j] for k in my half
  float Mreg[64];
  #pragma unroll
  for (int kk = 0; kk < 64; ++kk)
    Mreg[kk] = exp2f(s_trans[(kbase + kk) * Tt + j] * LOG2E);
  const float tSOS  = s_trans[SOS * Tt + j];
  const float tEOS2 = s_trans[j * Tt + EOS] * LOG2E;

  // ---- init: f0 = exp(trans[SOS,j] + em[b,0,j]) ----
  float fn = exp2f((tSOS + em[base + j]) * LOG2E);
  if (l < 32) s_f[0][j] = fn;
  float c_scale = 0.f;
  float em0 = em[base + (size_t)1 * Tt + j];   // for step 1
  float em1 = em[base + (size_t)2 * Tt + j];   // for step 2
  __syncthreads();

  // ---- main recurrence: one barrier per step ----
  for (int i = 1; i < Ss; ++i) {
    const int p = i & 1;
    // prefetch emission for step i+2 (clamped; coalesced 128B per wave)
    int ip = (i + 2 < Ss) ? (i + 2) : (Ss - 1);
    float em2 = em[base + (size_t)ip * Tt + j];
    float mi = s_mask[i];
    float fold = s_f[p ^ 1][j];

    // rescale apply (reads maxima measured last step, barrier-separated)
    float scl = 1.0f;
    if ((i & 3) == 1) {
      float4 r4 = *(float4*)&s_red[0];
      float M = fmaxf(fmaxf(r4.x, r4.y), fmaxf(r4.z, r4.w));
      int e; (void)frexpf(M, &e);                   // M = m * 2^e
      scl = __int_as_float((127 - e) << 23);        // 2^-e
      c_scale += (float)e;
    }
    float w_ = exp2f(em0 * LOG2E) * scl;            // emission weight (+scale)

    // 128-deep dot product: 64 broadcast LDS floats + 64 FMAs, 4 chains
    float acc0 = 0.f, acc1 = 0.f, acc2 = 0.f, acc3 = 0.f;
    const float4* fsrc = (const float4*)&s_f[p ^ 1][kbase];
    #pragma unroll
    for (int q = 0; q < 16; ++q) {
      float4 fv = fsrc[q];
      acc0 = fmaf(fv.x, Mreg[4 * q + 0], acc0);
      acc1 = fmaf(fv.y, Mreg[4 * q + 1], acc1);
      acc2 = fmaf(fv.z, Mreg[4 * q + 2], acc2);
      acc3 = fmaf(fv.w, Mreg[4 * q + 3], acc3);
    }
    float g = (acc0 + acc1) + (acc2 + acc3);
    g += __shfl_xor(g, 32);                         // combine the two k-halves

    float fnew = g * w_;
    fold *= scl;
    fn = (mi == 0.f) ? fold : fnew;                 // masked step: keep alpha
    if (l < 32) s_f[p][j] = fn;

    if ((i & 3) == 0) {                             // measure max for rescale
      float v = fn;
      #pragma unroll
      for (int o = 16; o > 0; o >>= 1) v = fmaxf(v, __shfl_xor(v, o));
      if (l == 0) s_red[w] = v;
    }
    em0 = em1; em1 = em2;
    __syncthreads();
  }

  // ---- partition = ln( sum_j f[j]*exp(trans[j,EOS]) ) + c*ln2 ----
  float v = (l < 32) ? fn * exp2f(tEOS2) : 0.f;
  #pragma unroll
  for (int o = 32; o > 0; o >>= 1) v += __shfl_xor(v, o);
  if (l == 0) s_red[w] = v;
  __syncthreads();
  if (tid == 0) {
    float s = (s_red[0] + s_red[1]) + (s_red[2] + s_red[3]);
    part_out[b] = (log2f(s) + c_scale) * LN2f;
  }
}

// ---------------------------------------------------------------------------
// Score (numerator) kernel: one block per batch element, gather + reduce.
// ---------------------------------------------------------------------------
__global__ __launch_bounds__(256) void crf_score(
    const float* __restrict__ em, const float* __restrict__ trans,
    const float* __restrict__ mask, const int* __restrict__ tags,
    float* __restrict__ sc)
{
  __shared__ float s_red[4];
  __shared__ float s_red2[4];
  const int tid = threadIdx.x;
  const int b = blockIdx.x;
  const size_t em_base = (size_t)b * Ss * Tt;
  const int* tg = tags + b * Ss;
  const float* mk = mask + b * Ss;

  float part = 0.f, msum = 0.f;
  for (int i = tid; i < Ss; i += 256) {
    float m = mk[i];
    msum += m;
    if (i >= 1) {
      int tc = tg[i], tp = tg[i - 1];
      part += m * (em[em_base + (size_t)i * Tt + tc] + trans[tp * Tt + tc]);
    }
  }
  #pragma unroll
  for (int o = 32; o > 0; o >>= 1) {
    part += __shfl_xor(part, o);
    msum += __shfl_xor(msum, o);
  }
  if ((tid & 63) == 0) { s_red[tid >> 6] = part; s_red2[tid >> 6] = msum; }
  __syncthreads();
  if (tid == 0) {
    float p  = s_red[0] + s_red[1] + s_red[2] + s_red[3];
    float ms = s_red2[0] + s_red2[1] + s_red2[2] + s_red2[3];
    int last = (int)(ms + 0.5f) - 1;
    int t0 = tg[0];
    float s = trans[SOS * Tt + t0] + em[em_base + t0] + p
            + trans[tg[last] * Tt + EOS];
    sc[b] = s;
  }
}

// ---------------------------------------------------------------------------
// Combine: out = sum_b (partition[b] - score[b])
// ---------------------------------------------------------------------------
__global__ __launch_bounds__(128) void crf_combine(
    const float* __restrict__ part, const float* __restrict__ sc,
    float* __restrict__ out)
{
  __shared__ float s_red[2];
  const int tid = threadIdx.x;
  float v = part[tid] - sc[tid];
  #pragma unroll
  for (int o = 32; o > 0; o >>= 1) v += __shfl_xor(v, o);
  if ((tid & 63) == 0) s_red[tid >> 6] = v;
  __syncthreads();
  if (tid == 0) out[0] = s_red[0] + s_red[1];
}

extern "C" void kernel_launch(void* const* d_in, const int* in_sizes, int n_in,
                              void* d_out, int out_size, void* d_ws, size_t ws_size,
                              hipStream_t stream)
{
  const float* em    = (const float*)d_in[0];
  const float* trans = (const float*)d_in[1];
  const float* mask  = (const float*)d_in[2];
  const int*   tags  = (const int*)d_in[3];
  float* out = (float*)d_out;
  float* wsf = (float*)d_ws;
  float* part = wsf;          // [128]
  float* sc   = wsf + 128;    // [128]

  hipLaunchKernelGGL(crf_score, dim3(Bb), dim3(256), 0, stream,
                     em, trans, mask, tags, sc);
  hipLaunchKernelGGL(crf_forward, dim3(Bb), dim3(256), 0, stream,
                     em, trans, mask, part);
  hipLaunchKernelGGL(crf_combine, dim3(1), dim3(128), 0, stream,
                     part, sc, out);
}